// Round 7
// baseline (129.897 us; speedup 1.0000x reference)
//
#include <hip/hip_runtime.h>

// ---- problem constants (fixed by reference setup_inputs) ----
constexpr int B_  = 32;
constexpr int Na  = 512;
constexpr int Nv  = 256;
constexpr int D   = 384;

constexpr int NK2 = D / 64;    // 6 k-chunks of 64 (one scaled MFMA each)

// fp8 operand regions, one 32-row group x 384 k = 12 KB per group.
// A-side (a8): unit kc (1 KB): byte = h2*512 + r*16 + j holding
//   value[row r][k = kc*32 + h2*16 + j]; MFMA lane l reads 16 B at l*16.
//   K=64 operand = unit 2q2 (regs0-3) + unit 2q2+1 (regs4-7): two
//   lane-contiguous ds_read_b128 (conflict-free baseline pattern).
// V-side (b8): k64-unit q2 (2 KB): lane l's 32 B contiguous at l*32 ->
//   ONE int8v global deref (2 coalesced dwordx4), no register shuffling.
// The (lane,byte)->k packing is IDENTICAL for A-slot and B-slot operands,
// so the contraction is exact under operand swap; scales = 1.0 (e8m0 0x7F)
// make the scaled MFMA numerically identical to non-scaled fp8.
constexpr int AGROUPS = B_ * 16;   // 512 groups (bi*16+rg), rows linear
constexpr int BGROUPS = B_ * 8;    // 256 groups (bj*8+cg), rows linear
constexpr size_t GROUP_BYTES = 12 * 1024;
constexpr int SCALE_ONE = 0x7F7F7F7F;   // e8m0 127 = 2^0 in every byte

typedef int   int4v    __attribute__((ext_vector_type(4)));
typedef int   int8v    __attribute__((ext_vector_type(8)));
typedef float floatx16 __attribute__((ext_vector_type(16)));

// 16B-per-lane async global->LDS (lane i writes LDS slot base + i*16)
__device__ __forceinline__ void async_load16(const void* g, void* l) {
    __builtin_amdgcn_global_load_lds(
        (const __attribute__((address_space(1))) unsigned int*)g,
        (__attribute__((address_space(3))) unsigned int*)l,
        16, 0, 0);
}

// ---- K1: zero output + fp32 -> fp8(e4m3 OCP) conversion, BOTH sides coalesced ----
__global__ void convert_fp8_kernel(const float* __restrict__ a, const float* __restrict__ v,
                                   unsigned char* __restrict__ a8,
                                   unsigned char* __restrict__ b8,
                                   float* __restrict__ out) {
    int gid = blockIdx.x * blockDim.x + threadIdx.x;
    if (gid < B_ * B_) out[gid] = 0.0f;    // d_out is poisoned before every launch

    const float* src;
    unsigned char* dst;
    int blk = blockIdx.x;
    const bool isA = blk < AGROUPS;
    if (isA) {                                 // A rows are linear: group*32 + r
        src = a + (size_t)blk * 32 * D;
        dst = a8 + (size_t)blk * GROUP_BYTES;
    } else {
        int b2 = blk - AGROUPS;
        src = v + (size_t)b2 * 32 * D;
        dst = b8 + (size_t)b2 * GROUP_BYTES;
    }
    const int t = threadIdx.x;
    const int r = t >> 3, q = t & 7;

    #pragma unroll
    for (int p = 0; p < 3; ++p) {
        int k0 = p * 128 + q * 16;
        const float4* s4 = (const float4*)(src + (size_t)r * D + k0);
        float4 f0 = s4[0], f1 = s4[1], f2 = s4[2], f3 = s4[3];
        int w0 = 0, w1 = 0, w2 = 0, w3 = 0;
        w0 = __builtin_amdgcn_cvt_pk_fp8_f32(f0.x, f0.y, w0, false);
        w0 = __builtin_amdgcn_cvt_pk_fp8_f32(f0.z, f0.w, w0, true);
        w1 = __builtin_amdgcn_cvt_pk_fp8_f32(f1.x, f1.y, w1, false);
        w1 = __builtin_amdgcn_cvt_pk_fp8_f32(f1.z, f1.w, w1, true);
        w2 = __builtin_amdgcn_cvt_pk_fp8_f32(f2.x, f2.y, w2, false);
        w2 = __builtin_amdgcn_cvt_pk_fp8_f32(f2.z, f2.w, w2, true);
        w3 = __builtin_amdgcn_cvt_pk_fp8_f32(f3.x, f3.y, w3, false);
        w3 = __builtin_amdgcn_cvt_pk_fp8_f32(f3.z, f3.w, w3, true);
        int kc = k0 >> 5;
        int h2 = (k0 >> 4) & 1;
        size_t off;
        if (isA) {
            off = (size_t)kc * 1024 + h2 * 512 + r * 16;            // A layout
        } else {
            int q2 = kc >> 1, u = kc & 1, l = r + 32 * h2;          // lane-32B units
            off = (size_t)q2 * 2048 + l * 32 + u * 16;
        }
        int4v o = { w0, w1, w2, w3 };
        *(int4v*)(dst + off) = o;   // wave's 64 stores still tile full 64B lines
    }
}

// sum of exp2(a[i] * 1/(tau*ln2)) over one accumulator, pairwise tree.
// RAW v_exp_f32: |x| <= ~60, inside the exact range of the HW instruction.
__device__ __forceinline__ float expsum16(floatx16 a) {
    constexpr float INV_TAU_LN2 = 0.7213475204444817f;  // 1/(tau*ln2), tau=2
    float e[16];
    #pragma unroll
    for (int i = 0; i < 16; ++i)
        e[i] = __builtin_amdgcn_exp2f(a[i] * INV_TAU_LN2);
    float t0 = (e[0] + e[1])  + (e[2] + e[3]);
    float t1 = (e[4] + e[5])  + (e[6] + e[7]);
    float t2 = (e[8] + e[9])  + (e[10] + e[11]);
    float t3 = (e[12] + e[13]) + (e[14] + e[15]);
    return (t0 + t1) + (t2 + t3);
}

// ---- K2: fused MX-scaled fp8 GEMM + lse-pool. PORT-BALANCED acc[4][2]. ----
// R6 post-mortem: 32x32x64 MFMA saturation needs 238 B/cy/CU of operands;
// ports give VMEM 64 + LDS 112 = 176. acc[2][2] put 50% of traffic on VMEM
// -> 93% port load = the wall. acc[4][2] (reuse 2.67): per chunk A 8 KB from
// LDS (53% of LDS port), V 4 KB from VMEM (47% of VMEM port) -> MFMA becomes
// the binding pipe. Wave = 128 audio x 64 v (128 AGPR acc); block = 8 waves
// (2 wm x 4 wn) = 256 audio x 256 v; A (8 groups, 96 KB) staged to LDS once
// whole-K (ONE barrier). V direct-to-VGPR, distance-1 double buffer.
// ~205 unified regs -> 2 waves/SIMD; 112 KB LDS -> 1 block/CU (8 waves/CU).
// Per-chunk MFMA cover 549 cy/wave vs ds_read ~120 cy; wave-pair overlap
// covers V latency.
__global__ __launch_bounds__(512, 2) void gemm_lse_kernel(
        const unsigned char* __restrict__ a8,
        const unsigned char* __restrict__ b8,
        float* __restrict__ out)
{
    __shared__ unsigned char ldsA[96 * 1024];   // block's 8 A-groups, whole K
    __shared__ float ms[4][8][32];              // [v-quarter][a-group][row]

    const int tid  = threadIdx.x;
    const int lane = tid & 63;
    const int wv   = tid >> 6;       // 8 waves
    const int wm   = wv >> 2;        // audio half (128 rows = groups wm*4..+3)
    const int wn   = wv & 3;         // v quarter (64 v = groups wn*2, wn*2+1)

    // XCD-chunked decode: bi tied to blockIdx%8 => per-XCD L2 set =
    // A(4 bi) 786KB + B(all) 3.1MB ~= 3.9MB <= 4MB.
    int b = blockIdx.x;
    const int xcd   = b & 7;      b >>= 3;
    const int bi_lo = b & 3;      b >>= 2;
    const int rb    = b & 1;      b >>= 1;   // row-block: 256 audio rows
    const int bj    = b;                      // 0..31
    const int bi    = xcd * 4 + bi_lo;        // 0..31

    // ---- stage A once: 96 KB (groups bi*16+rb*8 .. +7); wave wv stages group wv ----
    {
        const unsigned char* gsrc = a8 + (size_t)(bi * 16 + rb * 8 + wv) * GROUP_BYTES
                                       + (size_t)lane * 16;
        unsigned char* ldst = ldsA + (size_t)wv * GROUP_BYTES;
        #pragma unroll
        for (int kc = 0; kc < 12; ++kc)
            async_load16(gsrc + (size_t)kc * 1024, ldst + kc * 1024);
    }
    __syncthreads();   // the ONLY staging barrier (A is static for the block)

    const unsigned char* pv0 = b8 + (size_t)(bj * 8 + wn * 2) * GROUP_BYTES
                                  + (size_t)lane * 32;
    const unsigned char* pv1 = pv0 + GROUP_BYTES;
    const unsigned char* la  = ldsA + (size_t)(wm * 4) * GROUP_BYTES
                                    + (size_t)lane * 16;

    floatx16 acc[4][2];   // [audio group][v group]
    #pragma unroll
    for (int g = 0; g < 4; ++g)
        #pragma unroll
        for (int vg = 0; vg < 2; ++vg)
            acc[g][vg] = (floatx16)(0.0f);

    int8v Vc0 = *(const int8v*)pv0;
    int8v Vc1 = *(const int8v*)pv1;

    #pragma unroll
    for (int q2 = 0; q2 < NK2; ++q2) {
        // distance-1 V prefetch (global, ~400 cy; covered by this chunk's MFMAs)
        int8v Vn0, Vn1;
        if (q2 + 1 < NK2) {
            Vn0 = *(const int8v*)(pv0 + (size_t)(q2 + 1) * 2048);
            Vn1 = *(const int8v*)(pv1 + (size_t)(q2 + 1) * 2048);
        }
        // A: 4 groups' k64 operands from LDS (8 lane-contiguous ds_read_b128)
        int8v A[4];
        #pragma unroll
        for (int g = 0; g < 4; ++g) {
            const unsigned char* p = la + (size_t)g * GROUP_BYTES + (size_t)q2 * 2048;
            int4v lo = *(const int4v*)p;
            int4v hi = *(const int4v*)(p + 1024);
            A[g] = __builtin_shufflevector(lo, hi, 0, 1, 2, 3, 4, 5, 6, 7);
        }
        // 8 MFMAs, 8 independent acc chains; V regs reused 4x, A regs 2x
        __builtin_amdgcn_s_setprio(1);
        #pragma unroll
        for (int g = 0; g < 4; ++g) {
            acc[g][0] = __builtin_amdgcn_mfma_scale_f32_32x32x64_f8f6f4(
                Vc0, A[g], acc[g][0], 0, 0, 0, SCALE_ONE, 0, SCALE_ONE);
            acc[g][1] = __builtin_amdgcn_mfma_scale_f32_32x32x64_f8f6f4(
                Vc1, A[g], acc[g][1], 0, 0, 0, SCALE_ONE, 0, SCALE_ONE);
        }
        __builtin_amdgcn_s_setprio(0);
        if (q2 + 1 < NK2) { Vc0 = Vn0; Vc1 = Vn1; }
    }

    // ---- epilogue: per-thread exp-sum over this wave's 64 v ----
    // C/D layout (shape-determined): audio row = lane&31 within a-group;
    // regs & lane>>5 = v indices. (no max: |sims/tau| <= ~55 -> exact)
    float s[4];
    #pragma unroll
    for (int g = 0; g < 4; ++g) {
        s[g] = expsum16(acc[g][0]) + expsum16(acc[g][1]);
        s[g] += __shfl_xor(s[g], 32);   // merge lane>>5 v-halves
    }
    if (lane < 32) {
        #pragma unroll
        for (int g = 0; g < 4; ++g)
            ms[wn][wm * 4 + g][lane] = s[g];
    }
    __syncthreads();

    // merge the 4 v-quarters (exp-space, linear -> exact), then lse + mean.
    // 256 block rows handled by 4 waves; one atomic per reducer wave.
    if (tid < 256) {
        const int g = tid >> 5, r = tid & 31;
        float e = (ms[0][g][r] + ms[1][g][r]) + (ms[2][g][r] + ms[3][g][r]);
        constexpr float TAU_LN2 = 1.3862943611198906f;  // tau*ln2 (v_log = log2)
        float lse = TAU_LN2 * __builtin_amdgcn_logf(e);
        #pragma unroll
        for (int m = 1; m < 64; m <<= 1) lse += __shfl_xor(lse, m);
        if ((tid & 63) == 0)
            atomicAdd(&out[bi * 32 + bj], lse * (1.0f / Na));  // 2rb x 4 = 8 adds
    }
}

extern "C" void kernel_launch(void* const* d_in, const int* in_sizes, int n_in,
                              void* d_out, int out_size, void* d_ws, size_t ws_size,
                              hipStream_t stream) {
    const float* audio  = (const float*)d_in[0];
    const float* visual = (const float*)d_in[1];
    float* out = (float*)d_out;

    unsigned char* a8 = (unsigned char*)d_ws;                        // 6.29 MB fp8 A
    unsigned char* b8 = a8 + (size_t)AGROUPS * GROUP_BYTES;          // +3.15 MB fp8 B

    convert_fp8_kernel<<<dim3(AGROUPS + BGROUPS), dim3(256), 0, stream>>>(
        audio, visual, a8, b8, out);
    // grid: 2048 blocks x 8 waves = 16384 waves
    //     = 32 bi x 32 bj x 2 row-blocks, block = 256 audio rows x 256 v
    gemm_lse_kernel<<<dim3(2048), dim3(512), 0, stream>>>(a8, b8, out);
}

// Round 8
// 126.154 us; speedup vs baseline: 1.0297x; 1.0297x over previous
//
#include <hip/hip_runtime.h>

// ---- problem constants (fixed by reference setup_inputs) ----
constexpr int B_  = 32;
constexpr int Na  = 512;
constexpr int Nv  = 256;
constexpr int D   = 384;

constexpr int NK2 = D / 64;    // 6 k-chunks of 64 (one scaled MFMA each)

// fp8 operand regions, one 32-row group x 384 k = 12 KB per group.
// A-side (a8): unit kc (1 KB): byte = h2*512 + r*16 + j holding
//   value[row r][k = kc*32 + h2*16 + j]; MFMA lane l reads 16 B at l*16.
//   K=64 operand = unit 2q2 (regs0-3) + unit 2q2+1 (regs4-7): two
//   lane-contiguous ds_read_b128 (conflict-free baseline pattern).
// V-side (b8): k64-unit q2 (2 KB): lane l's 32 B contiguous at l*32 ->
//   ONE int8v global deref (2 coalesced dwordx4), no register shuffling.
// The (lane,byte)->k packing is IDENTICAL for A-slot and B-slot operands,
// so the contraction is exact under operand swap; scales = 1.0 (e8m0 0x7F)
// make the scaled MFMA numerically identical to non-scaled fp8.
constexpr int AGROUPS = B_ * 16;   // 512 groups (bi*16+rg), rows linear
constexpr int BGROUPS = B_ * 8;    // 256 groups (bj*8+cg), rows linear
constexpr size_t GROUP_BYTES = 12 * 1024;
constexpr int SCALE_ONE = 0x7F7F7F7F;   // e8m0 127 = 2^0 in every byte

typedef int   int4v    __attribute__((ext_vector_type(4)));
typedef int   int8v    __attribute__((ext_vector_type(8)));
typedef float floatx16 __attribute__((ext_vector_type(16)));

// 16B-per-lane async global->LDS (lane i writes LDS slot base + i*16)
__device__ __forceinline__ void async_load16(const void* g, void* l) {
    __builtin_amdgcn_global_load_lds(
        (const __attribute__((address_space(1))) unsigned int*)g,
        (__attribute__((address_space(3))) unsigned int*)l,
        16, 0, 0);
}

// ---- K1: zero output + fp32 -> fp8(e4m3 OCP) conversion, BOTH sides coalesced ----
__global__ void convert_fp8_kernel(const float* __restrict__ a, const float* __restrict__ v,
                                   unsigned char* __restrict__ a8,
                                   unsigned char* __restrict__ b8,
                                   float* __restrict__ out) {
    int gid = blockIdx.x * blockDim.x + threadIdx.x;
    if (gid < B_ * B_) out[gid] = 0.0f;    // d_out is poisoned before every launch

    const float* src;
    unsigned char* dst;
    int blk = blockIdx.x;
    const bool isA = blk < AGROUPS;
    if (isA) {                                 // A rows are linear: group*32 + r
        src = a + (size_t)blk * 32 * D;
        dst = a8 + (size_t)blk * GROUP_BYTES;
    } else {
        int b2 = blk - AGROUPS;
        src = v + (size_t)b2 * 32 * D;
        dst = b8 + (size_t)b2 * GROUP_BYTES;
    }
    const int t = threadIdx.x;
    const int r = t >> 3, q = t & 7;

    #pragma unroll
    for (int p = 0; p < 3; ++p) {
        int k0 = p * 128 + q * 16;
        const float4* s4 = (const float4*)(src + (size_t)r * D + k0);
        float4 f0 = s4[0], f1 = s4[1], f2 = s4[2], f3 = s4[3];
        int w0 = 0, w1 = 0, w2 = 0, w3 = 0;
        w0 = __builtin_amdgcn_cvt_pk_fp8_f32(f0.x, f0.y, w0, false);
        w0 = __builtin_amdgcn_cvt_pk_fp8_f32(f0.z, f0.w, w0, true);
        w1 = __builtin_amdgcn_cvt_pk_fp8_f32(f1.x, f1.y, w1, false);
        w1 = __builtin_amdgcn_cvt_pk_fp8_f32(f1.z, f1.w, w1, true);
        w2 = __builtin_amdgcn_cvt_pk_fp8_f32(f2.x, f2.y, w2, false);
        w2 = __builtin_amdgcn_cvt_pk_fp8_f32(f2.z, f2.w, w2, true);
        w3 = __builtin_amdgcn_cvt_pk_fp8_f32(f3.x, f3.y, w3, false);
        w3 = __builtin_amdgcn_cvt_pk_fp8_f32(f3.z, f3.w, w3, true);
        int kc = k0 >> 5;
        int h2 = (k0 >> 4) & 1;
        size_t off;
        if (isA) {
            off = (size_t)kc * 1024 + h2 * 512 + r * 16;            // A layout
        } else {
            int q2 = kc >> 1, u = kc & 1, l = r + 32 * h2;          // lane-32B units
            off = (size_t)q2 * 2048 + l * 32 + u * 16;
        }
        int4v o = { w0, w1, w2, w3 };
        *(int4v*)(dst + off) = o;
    }
}

// sum of exp2(a[i] * 1/(tau*ln2)) over one accumulator, pairwise tree.
// RAW v_exp_f32: |x| <= ~60, inside the exact range of the HW instruction.
__device__ __forceinline__ float expsum16(floatx16 a) {
    constexpr float INV_TAU_LN2 = 0.7213475204444817f;  // 1/(tau*ln2), tau=2
    float e[16];
    #pragma unroll
    for (int i = 0; i < 16; ++i)
        e[i] = __builtin_amdgcn_exp2f(a[i] * INV_TAU_LN2);
    float t0 = (e[0] + e[1])  + (e[2] + e[3]);
    float t1 = (e[4] + e[5])  + (e[6] + e[7]);
    float t2 = (e[8] + e[9])  + (e[10] + e[11]);
    float t3 = (e[12] + e[13]) + (e[14] + e[15]);
    return (t0 + t1) + (t2 + t3);
}

// ---- K2: fused MX-scaled fp8 GEMM + lse-pool. 2-BLOCKS/CU STAGGER structure. ----
// R7 post-mortem: port balance was right but 96 KB LDS -> 1 block/CU ->
// CU-level phase lockstep: stage-expose + quarter-rate-TRANS epilogue tail
// serialize with MFMA 8 times (window 19.4k cy vs 6.6k MFMA per round).
// R6 had 2 blocks/CU but a 93%-saturated VMEM port. Union fix: keep R7's
// balanced wave tile (128 audio x 64 v; A 8KB/chunk from LDS = 53% port,
// V 4KB/chunk from VMEM = 47%), but block = 4 WAVES (1/SIMD) staging only
// 48 KB (4 A-groups). VGPR ~232 unified -> 2 waves/SIMD = 2 blocks/CU
// co-resident -> the other block's MFMAs cover this block's staging and
// epilogue. Amortized VMEM ~45 B/cy/CU (70%), LDS ~58 B/cy (60%), MFMA
// floor 22 us is the target pipe.
__global__ __launch_bounds__(256, 2) void gemm_lse_kernel(
        const unsigned char* __restrict__ a8,
        const unsigned char* __restrict__ b8,
        float* __restrict__ out)
{
    __shared__ unsigned char ldsA[48 * 1024];   // block's 4 A-groups, whole K
    __shared__ float ms[4][4][32];              // [v-quarter][a-group][row]

    const int tid  = threadIdx.x;
    const int lane = tid & 63;
    const int wn   = tid >> 6;       // 4 waves = 4 v-quarters (64 v each)

    // XCD-chunked decode: bi tied to blockIdx%8 => per-XCD L2 set =
    // A(4 bi) 786KB + B(all) 3.1MB ~= 3.9MB <= 4MB.
    int b = blockIdx.x;
    const int xcd   = b & 7;      b >>= 3;
    const int bi_lo = b & 3;      b >>= 2;
    const int rb    = b & 3;      b >>= 2;   // row-block: 128 audio rows
    const int bj    = b;                      // 0..31
    const int bi    = xcd * 4 + bi_lo;        // 0..31

    // ---- stage A once: 48 KB (groups bi*16+rb*4 .. +3); wave wn stages group wn ----
    {
        const unsigned char* gsrc = a8 + (size_t)(bi * 16 + rb * 4 + wn) * GROUP_BYTES
                                       + (size_t)lane * 16;
        unsigned char* ldst = ldsA + (size_t)wn * GROUP_BYTES;
        #pragma unroll
        for (int kc = 0; kc < 12; ++kc)
            async_load16(gsrc + (size_t)kc * 1024, ldst + kc * 1024);
    }
    __syncthreads();   // the ONLY staging barrier (A is static for the block)

    const unsigned char* pv0 = b8 + (size_t)(bj * 8 + wn * 2) * GROUP_BYTES
                                  + (size_t)lane * 32;
    const unsigned char* pv1 = pv0 + GROUP_BYTES;
    const unsigned char* la  = ldsA + (size_t)lane * 16;

    floatx16 acc[4][2];   // [audio group][v group]
    #pragma unroll
    for (int g = 0; g < 4; ++g)
        #pragma unroll
        for (int vg = 0; vg < 2; ++vg)
            acc[g][vg] = (floatx16)(0.0f);

    int8v Vc0 = *(const int8v*)pv0;
    int8v Vc1 = *(const int8v*)pv1;

    #pragma unroll
    for (int q2 = 0; q2 < NK2; ++q2) {
        // distance-1 V prefetch (global; covered by this chunk's 549-cy MFMA run)
        int8v Vn0, Vn1;
        if (q2 + 1 < NK2) {
            Vn0 = *(const int8v*)(pv0 + (size_t)(q2 + 1) * 2048);
            Vn1 = *(const int8v*)(pv1 + (size_t)(q2 + 1) * 2048);
        }
        // A: 4 groups' k64 operands from LDS (8 lane-contiguous ds_read_b128)
        int8v A[4];
        #pragma unroll
        for (int g = 0; g < 4; ++g) {
            const unsigned char* p = la + (size_t)g * GROUP_BYTES + (size_t)q2 * 2048;
            int4v lo = *(const int4v*)p;
            int4v hi = *(const int4v*)(p + 1024);
            A[g] = __builtin_shufflevector(lo, hi, 0, 1, 2, 3, 4, 5, 6, 7);
        }
        // 8 MFMAs, 8 independent acc chains; V regs reused 4x, A regs 2x
        __builtin_amdgcn_s_setprio(1);
        #pragma unroll
        for (int g = 0; g < 4; ++g) {
            acc[g][0] = __builtin_amdgcn_mfma_scale_f32_32x32x64_f8f6f4(
                Vc0, A[g], acc[g][0], 0, 0, 0, SCALE_ONE, 0, SCALE_ONE);
            acc[g][1] = __builtin_amdgcn_mfma_scale_f32_32x32x64_f8f6f4(
                Vc1, A[g], acc[g][1], 0, 0, 0, SCALE_ONE, 0, SCALE_ONE);
        }
        __builtin_amdgcn_s_setprio(0);
        if (q2 + 1 < NK2) { Vc0 = Vn0; Vc1 = Vn1; }
    }

    // ---- epilogue: per-thread exp-sum over this wave's 64 v ----
    // C/D layout (shape-determined): audio row = lane&31 within a-group;
    // regs & lane>>5 = v indices. (no max: |sims/tau| <= ~55 -> exact)
    float s[4];
    #pragma unroll
    for (int g = 0; g < 4; ++g) {
        s[g] = expsum16(acc[g][0]) + expsum16(acc[g][1]);
        s[g] += __shfl_xor(s[g], 32);   // merge lane>>5 v-halves
    }
    if (lane < 32) {
        #pragma unroll
        for (int g = 0; g < 4; ++g)
            ms[wn][g][lane] = s[g];
    }
    __syncthreads();

    // merge the 4 v-quarters (exp-space, linear -> exact), then lse + mean.
    // 128 block rows handled by 2 waves; one atomic per reducer wave.
    if (tid < 128) {
        const int g = tid >> 5, r = tid & 31;
        float e = (ms[0][g][r] + ms[1][g][r]) + (ms[2][g][r] + ms[3][g][r]);
        constexpr float TAU_LN2 = 1.3862943611198906f;  // tau*ln2 (v_log = log2)
        float lse = TAU_LN2 * __builtin_amdgcn_logf(e);
        #pragma unroll
        for (int m = 1; m < 64; m <<= 1) lse += __shfl_xor(lse, m);
        if ((tid & 63) == 0)
            atomicAdd(&out[bi * 32 + bj], lse * (1.0f / Na));  // 4rb x 2 = 8 adds
    }
}

extern "C" void kernel_launch(void* const* d_in, const int* in_sizes, int n_in,
                              void* d_out, int out_size, void* d_ws, size_t ws_size,
                              hipStream_t stream) {
    const float* audio  = (const float*)d_in[0];
    const float* visual = (const float*)d_in[1];
    float* out = (float*)d_out;

    unsigned char* a8 = (unsigned char*)d_ws;                        // 6.29 MB fp8 A
    unsigned char* b8 = a8 + (size_t)AGROUPS * GROUP_BYTES;          // +3.15 MB fp8 B

    convert_fp8_kernel<<<dim3(AGROUPS + BGROUPS), dim3(256), 0, stream>>>(
        audio, visual, a8, b8, out);
    // grid: 4096 blocks x 4 waves = 16384 waves
    //     = 32 bi x 32 bj x 4 row-blocks, block = 128 audio rows x 256 v
    gemm_lse_kernel<<<dim3(4096), dim3(256), 0, stream>>>(a8, b8, out);
}